// Round 1
// baseline (367.667 us; speedup 1.0000x reference)
//
#include <hip/hip_runtime.h>
#include <hip/hip_bf16.h>

typedef __attribute__((ext_vector_type(4))) float f32x4;
typedef __attribute__((ext_vector_type(8))) short s16x8;
typedef __attribute__((ext_vector_type(4))) short s16x4;
typedef __attribute__((ext_vector_type(4))) float f32x4v;

#define AS1 __attribute__((address_space(1)))
#define AS3 __attribute__((address_space(3)))

__device__ __forceinline__ short f2bf(float f) {
    union { float f; unsigned u; } a; a.f = f;
    unsigned r = a.u + 0x7fff + ((a.u >> 16) & 1);
    return (short)(r >> 16);
}

// ---------------- conversion kernels ----------------

__global__ __launch_bounds__(256) void convert_f32_bf16(const float* __restrict__ in,
                                                        short* __restrict__ out, int n4) {
    int i = blockIdx.x * 256 + threadIdx.x;
    if (i < n4) {
        f32x4 v = *(const f32x4*)(in + (long)i * 4);
        s16x4 o;
        o.x = f2bf(v.x); o.y = f2bf(v.y); o.z = f2bf(v.z); o.w = f2bf(v.w);
        *(s16x4*)(out + (long)i * 4) = o;
    }
}

// src [K][N] f32 -> dst [N][K] bf16
__global__ __launch_bounds__(256) void transpose_w(const float* __restrict__ src,
                                                   short* __restrict__ dst, int K, int N) {
    __shared__ short t[64][65];
    int k0 = blockIdx.x * 64, n0 = blockIdx.y * 64;
    int tid = threadIdx.x;
    for (int i = tid; i < 64 * 64; i += 256) {
        int r = i >> 6, c = i & 63;
        t[r][c] = f2bf(src[(long)(k0 + r) * N + n0 + c]);
    }
    __syncthreads();
    for (int i = tid; i < 64 * 64; i += 256) {
        int r = i >> 6, c = i & 63;
        dst[(long)(n0 + r) * K + k0 + c] = t[c][r];
    }
}

// ---------------- GEMM: C = A @ BT^T + bias ----------------
// A [M][K] bf16 row-major, BT [N][K] bf16 row-major.
// MODE 0: f32 out + bias.  MODE 1: bf16 out + bias, cols<768 scaled by 0.125 (q-scale fold)

template <int MODE>
__global__ __launch_bounds__(256) void gemm_bt(const short* __restrict__ A,
                                               const short* __restrict__ BT,
                                               const float* __restrict__ bias,
                                               float* __restrict__ outF,
                                               short* __restrict__ outH,
                                               int M, int N, int K) {
    __shared__ short lA[128 * 32];
    __shared__ short lB[128 * 32];
    int tid = threadIdx.x;
    int lane = tid & 63, w = tid >> 6;
    int wr = w >> 1, wc = w & 1;
    int lo = lane & 15, hi = lane >> 4;
    int m0 = blockIdx.y * 128, n0 = blockIdx.x * 128;

    f32x4 acc[4][4];
#pragma unroll
    for (int i = 0; i < 4; ++i)
#pragma unroll
        for (int j = 0; j < 4; ++j) acc[i][j] = (f32x4){0.f, 0.f, 0.f, 0.f};

    const short* Abase = A + (long)m0 * K;
    const short* Bbase = BT + (long)n0 * K;

    for (int k0 = 0; k0 < K; k0 += 32) {
        __syncthreads();
#pragma unroll
        for (int i = 0; i < 2; ++i) {
            int c = (w * 2 + i) * 64 + lane;
            const short* ga = Abase + (long)(c >> 2) * K + k0 + (c & 3) * 8;
            const short* gb = Bbase + (long)(c >> 2) * K + k0 + (c & 3) * 8;
            __builtin_amdgcn_global_load_lds((const AS1 void*)ga,
                                             (AS3 void*)(lA + (w * 2 + i) * 512), 16, 0, 0);
            __builtin_amdgcn_global_load_lds((const AS1 void*)gb,
                                             (AS3 void*)(lB + (w * 2 + i) * 512), 16, 0, 0);
        }
        __syncthreads();

        s16x8 a[4], b[4];
#pragma unroll
        for (int mi = 0; mi < 4; ++mi)
            a[mi] = *(const s16x8*)(lA + (wr * 64 + mi * 16 + lo) * 32 + hi * 8);
#pragma unroll
        for (int ni = 0; ni < 4; ++ni)
            b[ni] = *(const s16x8*)(lB + (wc * 64 + ni * 16 + lo) * 32 + hi * 8);
#pragma unroll
        for (int mi = 0; mi < 4; ++mi)
#pragma unroll
            for (int ni = 0; ni < 4; ++ni)
                acc[mi][ni] = __builtin_amdgcn_mfma_f32_16x16x32_bf16(a[mi], b[ni], acc[mi][ni], 0, 0, 0);
    }

#pragma unroll
    for (int mi = 0; mi < 4; ++mi)
#pragma unroll
        for (int ni = 0; ni < 4; ++ni)
#pragma unroll
            for (int r = 0; r < 4; ++r) {
                int gm = m0 + wr * 64 + mi * 16 + hi * 4 + r;
                int gn = n0 + wc * 64 + ni * 16 + lo;
                float v = acc[mi][ni][r] + bias[gn];
                if (MODE == 1) {
                    if (gn < 768) v *= 0.125f;
                    outH[(long)gm * N + gn] = f2bf(v);
                } else {
                    outF[(long)gm * N + gn] = v;
                }
            }
}

// ---------------- flash attention ----------------
// qkv [B*T][2304] bf16 (q scaled by 0.125 already). y [B*T][768] bf16, col = h*64+d.
// grid (qt=16, h=12, b=16), 256 threads (4 waves, 16 q-rows each), KV tiles of 64.

__global__ __launch_bounds__(256) void flash_attn(const short* __restrict__ qkv,
                                                  short* __restrict__ y) {
    __shared__ short Kt[64][72];   // [kv][d]
    __shared__ short Vt[64][72];   // [d][kv]  (transposed V)
    __shared__ short Pb[4][16][72];

    int tid = threadIdx.x;
    int lane = tid & 63, w = tid >> 6;
    int lo = lane & 15, hi = lane >> 4;
    int qt = blockIdx.x, h = blockIdx.y, b = blockIdx.z;
    long rowbase = (long)b * 1024;
    int qrow0 = qt * 64 + w * 16;  // first q row of this wave (within seq)

    s16x8 aq[2];
#pragma unroll
    for (int kc = 0; kc < 2; ++kc)
        aq[kc] = *(const s16x8*)(qkv + (rowbase + qrow0 + lo) * 2304 + h * 64 + kc * 32 + hi * 8);

    f32x4 ov[4];
#pragma unroll
    for (int i = 0; i < 4; ++i) ov[i] = (f32x4){0.f, 0.f, 0.f, 0.f};
    float mrow[4], lrow[4];
#pragma unroll
    for (int r = 0; r < 4; ++r) { mrow[r] = -3.0e38f; lrow[r] = 0.f; }

    int kvEnd = qt * 64 + 64;
    for (int kv0 = 0; kv0 < kvEnd; kv0 += 64) {
        __syncthreads();
        // stage K tile and transposed V tile
#pragma unroll
        for (int i = 0; i < 2; ++i) {
            int j = tid + i * 256;
            int r = j >> 3, ch = j & 7;
            *(s16x8*)(&Kt[r][ch * 8]) =
                *(const s16x8*)(qkv + (rowbase + kv0 + r) * 2304 + 768 + h * 64 + ch * 8);
            s16x8 vv = *(const s16x8*)(qkv + (rowbase + kv0 + r) * 2304 + 1536 + h * 64 + ch * 8);
#pragma unroll
            for (int e = 0; e < 8; ++e) Vt[ch * 8 + e][r] = vv[e];
        }
        __syncthreads();

        bool active = kv0 <= qrow0 + 15;
        if (active) {
            // S = Q K^T  (16 q-rows x 64 kv-cols)
            f32x4 s[4];
#pragma unroll
            for (int n = 0; n < 4; ++n) {
                s16x8 bk0 = *(const s16x8*)(&Kt[n * 16 + lo][hi * 8]);
                s16x8 bk1 = *(const s16x8*)(&Kt[n * 16 + lo][32 + hi * 8]);
                f32x4 t = (f32x4){0.f, 0.f, 0.f, 0.f};
                t = __builtin_amdgcn_mfma_f32_16x16x32_bf16(aq[0], bk0, t, 0, 0, 0);
                t = __builtin_amdgcn_mfma_f32_16x16x32_bf16(aq[1], bk1, t, 0, 0, 0);
                s[n] = t;
            }
            bool needMask = (kv0 + 63) > qrow0;
            if (needMask) {
#pragma unroll
                for (int n = 0; n < 4; ++n)
#pragma unroll
                    for (int r = 0; r < 4; ++r) {
                        int qr = qrow0 + hi * 4 + r;
                        int kc = kv0 + n * 16 + lo;
                        if (kc > qr) s[n][r] = -3.0e38f;
                    }
            }
            // online softmax
            float alpha[4];
#pragma unroll
            for (int r = 0; r < 4; ++r) {
                float v = fmaxf(fmaxf(s[0][r], s[1][r]), fmaxf(s[2][r], s[3][r]));
                v = fmaxf(v, __shfl_xor(v, 1));
                v = fmaxf(v, __shfl_xor(v, 2));
                v = fmaxf(v, __shfl_xor(v, 4));
                v = fmaxf(v, __shfl_xor(v, 8));
                float mn = fmaxf(mrow[r], v);
                alpha[r] = __expf(mrow[r] - mn);
                mrow[r] = mn;
            }
            float rs[4] = {0.f, 0.f, 0.f, 0.f};
#pragma unroll
            for (int n = 0; n < 4; ++n)
#pragma unroll
                for (int r = 0; r < 4; ++r) {
                    float p = __expf(s[n][r] - mrow[r]);
                    rs[r] += p;
                    Pb[w][hi * 4 + r][n * 16 + lo] = f2bf(p);
                }
#pragma unroll
            for (int r = 0; r < 4; ++r) {
                float v = rs[r];
                v += __shfl_xor(v, 1);
                v += __shfl_xor(v, 2);
                v += __shfl_xor(v, 4);
                v += __shfl_xor(v, 8);
                lrow[r] = lrow[r] * alpha[r] + v;
#pragma unroll
                for (int nd = 0; nd < 4; ++nd) ov[nd][r] *= alpha[r];
            }
            // O += P V   (P read back in A-frag layout from wave-private LDS)
            s16x8 ap0 = *(const s16x8*)(&Pb[w][lo][hi * 8]);
            s16x8 ap1 = *(const s16x8*)(&Pb[w][lo][32 + hi * 8]);
#pragma unroll
            for (int nd = 0; nd < 4; ++nd) {
                s16x8 bv0 = *(const s16x8*)(&Vt[nd * 16 + lo][hi * 8]);
                s16x8 bv1 = *(const s16x8*)(&Vt[nd * 16 + lo][32 + hi * 8]);
                ov[nd] = __builtin_amdgcn_mfma_f32_16x16x32_bf16(ap0, bv0, ov[nd], 0, 0, 0);
                ov[nd] = __builtin_amdgcn_mfma_f32_16x16x32_bf16(ap1, bv1, ov[nd], 0, 0, 0);
            }
        }
    }
    // epilogue: O / l -> y
#pragma unroll
    for (int nd = 0; nd < 4; ++nd)
#pragma unroll
        for (int r = 0; r < 4; ++r) {
            float v = ov[nd][r] / lrow[r];
            y[(rowbase + qrow0 + hi * 4 + r) * 768 + h * 64 + nd * 16 + lo] = f2bf(v);
        }
}

// ---------------- launch ----------------

extern "C" void kernel_launch(void* const* d_in, const int* in_sizes, int n_in,
                              void* d_out, int out_size, void* d_ws, size_t ws_size,
                              hipStream_t stream) {
    const float* x      = (const float*)d_in[0];
    const float* w_attn = (const float*)d_in[1];
    const float* b_attn = (const float*)d_in[2];
    const float* w_proj = (const float*)d_in[3];
    const float* b_proj = (const float*)d_in[4];

    char* ws = (char*)d_ws;
    short* x_bf = (short*)ws;                      // 16384*768*2   = 25165824
    short* qkv  = (short*)(ws + 25165824);         // 16384*2304*2  = 75497472
    short* yb   = (short*)(ws + 100663296);        // 16384*768*2   = 25165824
    short* waT  = (short*)(ws + 125829120);        // 2304*768*2    = 3538944
    short* wpT  = (short*)(ws + 129368064);        // 768*768*2     = 1179648

    // x -> bf16
    convert_f32_bf16<<<dim3(12288), dim3(256), 0, stream>>>(x, x_bf, 3145728);
    // weight transposes (to [N][K] bf16)
    transpose_w<<<dim3(12, 36), dim3(256), 0, stream>>>(w_attn, waT, 768, 2304);
    transpose_w<<<dim3(12, 12), dim3(256), 0, stream>>>(w_proj, wpT, 768, 768);
    // QKV projection (+bias, q scaled by 1/8)
    gemm_bt<1><<<dim3(18, 128), dim3(256), 0, stream>>>(x_bf, waT, b_attn,
                                                        (float*)nullptr, qkv, 16384, 2304, 768);
    // causal flash attention
    flash_attn<<<dim3(16, 12, 16), dim3(256), 0, stream>>>(qkv, yb);
    // output projection -> fp32
    gemm_bt<0><<<dim3(6, 128), dim3(256), 0, stream>>>(yb, wpT, b_proj,
                                                       (float*)d_out, (short*)nullptr, 16384, 768, 768);
}

// Round 2
// 339.059 us; speedup vs baseline: 1.0844x; 1.0844x over previous
//
#include <hip/hip_runtime.h>
#include <hip/hip_bf16.h>

typedef __attribute__((ext_vector_type(4))) float f32x4;
typedef __attribute__((ext_vector_type(8))) short s16x8;
typedef __attribute__((ext_vector_type(4))) short s16x4;

#define AS1 __attribute__((address_space(1)))
#define AS3 __attribute__((address_space(3)))

__device__ __forceinline__ short f2bf(float f) {
    union { float f; unsigned u; } a; a.f = f;
    unsigned r = a.u + 0x7fff + ((a.u >> 16) & 1);
    return (short)(r >> 16);
}

// ---------------- conversion kernels ----------------

__global__ __launch_bounds__(256) void convert_f32_bf16(const float* __restrict__ in,
                                                        short* __restrict__ out, int n4) {
    int i = blockIdx.x * 256 + threadIdx.x;
    if (i < n4) {
        f32x4 v = *(const f32x4*)(in + (long)i * 4);
        s16x4 o;
        o.x = f2bf(v.x); o.y = f2bf(v.y); o.z = f2bf(v.z); o.w = f2bf(v.w);
        *(s16x4*)(out + (long)i * 4) = o;
    }
}

// src [K][N] f32 -> dst [N][K] bf16
__global__ __launch_bounds__(256) void transpose_w(const float* __restrict__ src,
                                                   short* __restrict__ dst, int K, int N) {
    __shared__ short t[64][65];
    int k0 = blockIdx.x * 64, n0 = blockIdx.y * 64;
    int tid = threadIdx.x;
    for (int i = tid; i < 64 * 64; i += 256) {
        int r = i >> 6, c = i & 63;
        t[r][c] = f2bf(src[(long)(k0 + r) * N + n0 + c]);
    }
    __syncthreads();
    for (int i = tid; i < 64 * 64; i += 256) {
        int r = i >> 6, c = i & 63;
        dst[(long)(n0 + r) * K + k0 + c] = t[c][r];
    }
}

// V part of qkv [B*T][2304] -> vt [(b*12+h)*64 + d][1024] (V^T per head)
__global__ __launch_bounds__(256) void transpose_v(const short* __restrict__ qkv,
                                                   short* __restrict__ vt) {
    __shared__ short t[64][72];
    int t0 = blockIdx.x * 64;
    int h = blockIdx.y, b = blockIdx.z;
    int tid = threadIdx.x;
#pragma unroll
    for (int i = 0; i < 2; ++i) {
        int j = tid + i * 256;
        int r = j >> 3, c = j & 7;
        s16x8 v = *(const s16x8*)(qkv + (long)(b * 1024 + t0 + r) * 2304 + 1536 + h * 64 + c * 8);
#pragma unroll
        for (int e = 0; e < 8; ++e) t[c * 8 + e][r] = v[e];
    }
    __syncthreads();
#pragma unroll
    for (int i = 0; i < 2; ++i) {
        int j = tid + i * 256;
        int r = j >> 3, c = j & 7;
        *(s16x8*)(vt + ((long)(b * 12 + h) * 64 + r) * 1024 + t0 + c * 8) = *(const s16x8*)&t[r][c * 8];
    }
}

// ---------------- GEMM: C = A @ BT^T + bias ----------------
// MODE 0: f32 out + bias.  MODE 1: bf16 out + bias, cols<768 scaled (q-scale * log2e fold)

template <int MODE>
__global__ __launch_bounds__(256) void gemm_bt(const short* __restrict__ A,
                                               const short* __restrict__ BT,
                                               const float* __restrict__ bias,
                                               float* __restrict__ outF,
                                               short* __restrict__ outH,
                                               int M, int N, int K) {
    __shared__ short lA[128 * 32];
    __shared__ short lB[128 * 32];
    int tid = threadIdx.x;
    int lane = tid & 63, w = tid >> 6;
    int wr = w >> 1, wc = w & 1;
    int lo = lane & 15, hi = lane >> 4;
    int m0 = blockIdx.y * 128, n0 = blockIdx.x * 128;

    f32x4 acc[4][4];
#pragma unroll
    for (int i = 0; i < 4; ++i)
#pragma unroll
        for (int j = 0; j < 4; ++j) acc[i][j] = (f32x4){0.f, 0.f, 0.f, 0.f};

    const short* Abase = A + (long)m0 * K;
    const short* Bbase = BT + (long)n0 * K;

    for (int k0 = 0; k0 < K; k0 += 32) {
        __syncthreads();
#pragma unroll
        for (int i = 0; i < 2; ++i) {
            int c = (w * 2 + i) * 64 + lane;
            const short* ga = Abase + (long)(c >> 2) * K + k0 + (c & 3) * 8;
            const short* gb = Bbase + (long)(c >> 2) * K + k0 + (c & 3) * 8;
            __builtin_amdgcn_global_load_lds((const AS1 void*)ga,
                                             (AS3 void*)(lA + (w * 2 + i) * 512), 16, 0, 0);
            __builtin_amdgcn_global_load_lds((const AS1 void*)gb,
                                             (AS3 void*)(lB + (w * 2 + i) * 512), 16, 0, 0);
        }
        __syncthreads();

        s16x8 a[4], b[4];
#pragma unroll
        for (int mi = 0; mi < 4; ++mi)
            a[mi] = *(const s16x8*)(lA + (wr * 64 + mi * 16 + lo) * 32 + hi * 8);
#pragma unroll
        for (int ni = 0; ni < 4; ++ni)
            b[ni] = *(const s16x8*)(lB + (wc * 64 + ni * 16 + lo) * 32 + hi * 8);
#pragma unroll
        for (int mi = 0; mi < 4; ++mi)
#pragma unroll
            for (int ni = 0; ni < 4; ++ni)
                acc[mi][ni] = __builtin_amdgcn_mfma_f32_16x16x32_bf16(a[mi], b[ni], acc[mi][ni], 0, 0, 0);
    }

#pragma unroll
    for (int mi = 0; mi < 4; ++mi)
#pragma unroll
        for (int ni = 0; ni < 4; ++ni)
#pragma unroll
            for (int r = 0; r < 4; ++r) {
                int gm = m0 + wr * 64 + mi * 16 + hi * 4 + r;
                int gn = n0 + wc * 64 + ni * 16 + lo;
                float v = acc[mi][ni][r] + bias[gn];
                if (MODE == 1) {
                    if (gn < 768) v *= 0.180336880f;  // (1/8) * log2(e)
                    outH[(long)gm * N + gn] = f2bf(v);
                } else {
                    outF[(long)gm * N + gn] = v;
                }
            }
}

// ---------------- flash attention v2 ----------------
// qkv [B*T][2304] bf16 (q pre-scaled by 0.125*log2e). vtg = V^T per head [(b*12+h)*64+d][1024].
// y [B*T][768] bf16. grid (qb=8, h=12, b=16), 256 thr = 4 waves x 32 q-rows, KV tiles 64,
// double-buffered swizzled LDS, reg-staged prefetch, 1 barrier/tile.

__global__ __launch_bounds__(256) void flash_attn2(const short* __restrict__ qkv,
                                                   const short* __restrict__ vtg,
                                                   short* __restrict__ y) {
    __shared__ short Kt[2][64 * 64];
    __shared__ short Vt[2][64 * 64];
    __shared__ short Pb[4][32][72];

    int tid = threadIdx.x;
    int lane = tid & 63, w = tid >> 6;
    int lo = lane & 15, hi = lane >> 4;
    int qb = blockIdx.x, h = blockIdx.y, b = blockIdx.z;
    long rowbase = (long)b * 1024;
    int qrow0 = qb * 128 + w * 32;
    const short* kbase = qkv + rowbase * 2304 + 768 + h * 64;
    const short* vbase = vtg + (long)(b * 12 + h) * 64 * 1024;

    // staging geometry: 512 chunks of 16B per tile; thread covers rows sr and sr+32
    int sr = tid >> 3;   // 0..31
    int sc = tid & 7;    // 16B chunk within 128B row
    int so0 = sr * 64 + ((sc * 8) ^ ((sr & 7) << 3));
    int so1 = so0 + 32 * 64;   // (sr+32)&7 == sr&7

    // Q fragments (2 m-frags x 2 k-chunks)
    s16x8 aq[2][2];
#pragma unroll
    for (int mi = 0; mi < 2; ++mi)
#pragma unroll
        for (int kc = 0; kc < 2; ++kc)
            aq[mi][kc] = *(const s16x8*)(qkv + (rowbase + qrow0 + mi * 16 + lo) * 2304 +
                                         h * 64 + kc * 32 + hi * 8);

    f32x4 ov[2][4];
    float mrow[2][4], lrow[2][4];
#pragma unroll
    for (int mi = 0; mi < 2; ++mi)
#pragma unroll
        for (int i = 0; i < 4; ++i) {
            ov[mi][i] = (f32x4){0.f, 0.f, 0.f, 0.f};
            mrow[mi][i] = -3.0e38f;
            lrow[mi][i] = 0.f;
        }

    int kvEnd = qb * 128 + 128;

    // prologue: stage tile 0 into buf 0
    {
        s16x8 k0r = *(const s16x8*)(kbase + (long)sr * 2304 + sc * 8);
        s16x8 k1r = *(const s16x8*)(kbase + (long)(sr + 32) * 2304 + sc * 8);
        s16x8 v0r = *(const s16x8*)(vbase + (long)sr * 1024 + sc * 8);
        s16x8 v1r = *(const s16x8*)(vbase + (long)(sr + 32) * 1024 + sc * 8);
        *(s16x8*)(Kt[0] + so0) = k0r;
        *(s16x8*)(Kt[0] + so1) = k1r;
        *(s16x8*)(Vt[0] + so0) = v0r;
        *(s16x8*)(Vt[0] + so1) = v1r;
    }
    __syncthreads();

    int cur = 0;
    for (int kv0 = 0; kv0 < kvEnd; kv0 += 64) {
        int nxt = kv0 + 64;
        bool pre = nxt < kvEnd;
        s16x8 k0r, k1r, v0r, v1r;
        if (pre) {   // issue next-tile global loads early (latency hides under compute)
            k0r = *(const s16x8*)(kbase + (long)(nxt + sr) * 2304 + sc * 8);
            k1r = *(const s16x8*)(kbase + (long)(nxt + sr + 32) * 2304 + sc * 8);
            v0r = *(const s16x8*)(vbase + (long)sr * 1024 + nxt + sc * 8);
            v1r = *(const s16x8*)(vbase + (long)(sr + 32) * 1024 + nxt + sc * 8);
        }

        if (kv0 <= qrow0 + 31) {
            const short* KT = Kt[cur];
            const short* VT = Vt[cur];
            // S = Q K^T
            f32x4 s[2][4];
#pragma unroll
            for (int n = 0; n < 4; ++n) {
                int row = n * 16 + lo;
                int xr = (row & 7) << 3;
                s16x8 bk0 = *(const s16x8*)(KT + row * 64 + ((hi * 8) ^ xr));
                s16x8 bk1 = *(const s16x8*)(KT + row * 64 + ((32 + hi * 8) ^ xr));
#pragma unroll
                for (int mi = 0; mi < 2; ++mi) {
                    f32x4 t = (n == 0 || true) ? (f32x4){0.f, 0.f, 0.f, 0.f} : s[mi][n];
                    t = __builtin_amdgcn_mfma_f32_16x16x32_bf16(aq[mi][0], bk0, t, 0, 0, 0);
                    t = __builtin_amdgcn_mfma_f32_16x16x32_bf16(aq[mi][1], bk1, t, 0, 0, 0);
                    s[mi][n] = t;
                }
            }
            bool needMask = (kv0 + 63) > qrow0;
#pragma unroll
            for (int mi = 0; mi < 2; ++mi) {
                if (needMask) {
#pragma unroll
                    for (int n = 0; n < 4; ++n)
#pragma unroll
                        for (int r = 0; r < 4; ++r) {
                            int qr = qrow0 + mi * 16 + hi * 4 + r;
                            int kc2 = kv0 + n * 16 + lo;
                            if (kc2 > qr) s[mi][n][r] = -3.0e38f;
                        }
                }
                float alpha[4];
#pragma unroll
                for (int r = 0; r < 4; ++r) {
                    float v = fmaxf(fmaxf(s[mi][0][r], s[mi][1][r]),
                                    fmaxf(s[mi][2][r], s[mi][3][r]));
                    v = fmaxf(v, __shfl_xor(v, 1));
                    v = fmaxf(v, __shfl_xor(v, 2));
                    v = fmaxf(v, __shfl_xor(v, 4));
                    v = fmaxf(v, __shfl_xor(v, 8));
                    float mn = fmaxf(mrow[mi][r], v);
                    alpha[r] = exp2f(mrow[mi][r] - mn);
                    mrow[mi][r] = mn;
                }
                float rs[4] = {0.f, 0.f, 0.f, 0.f};
#pragma unroll
                for (int n = 0; n < 4; ++n)
#pragma unroll
                    for (int r = 0; r < 4; ++r) {
                        float p = exp2f(s[mi][n][r] - mrow[mi][r]);
                        rs[r] += p;
                        Pb[w][mi * 16 + hi * 4 + r][n * 16 + lo] = f2bf(p);
                    }
#pragma unroll
                for (int r = 0; r < 4; ++r) {
                    float v = rs[r];
                    v += __shfl_xor(v, 1);
                    v += __shfl_xor(v, 2);
                    v += __shfl_xor(v, 4);
                    v += __shfl_xor(v, 8);
                    lrow[mi][r] = lrow[mi][r] * alpha[r] + v;
#pragma unroll
                    for (int nd = 0; nd < 4; ++nd) ov[mi][nd][r] *= alpha[r];
                }
            }
            // O += P V
            s16x8 ap[2][2];
#pragma unroll
            for (int mi = 0; mi < 2; ++mi)
#pragma unroll
                for (int kc = 0; kc < 2; ++kc)
                    ap[mi][kc] = *(const s16x8*)&Pb[w][mi * 16 + lo][kc * 32 + hi * 8];
#pragma unroll
            for (int nd = 0; nd < 4; ++nd) {
                int row = nd * 16 + lo;
                int xr = (row & 7) << 3;
#pragma unroll
                for (int kc = 0; kc < 2; ++kc) {
                    s16x8 bv = *(const s16x8*)(VT + row * 64 + ((kc * 32 + hi * 8) ^ xr));
#pragma unroll
                    for (int mi = 0; mi < 2; ++mi)
                        ov[mi][nd] = __builtin_amdgcn_mfma_f32_16x16x32_bf16(ap[mi][kc], bv,
                                                                             ov[mi][nd], 0, 0, 0);
                }
            }
        }

        if (pre) {
            short* Kn = Kt[cur ^ 1];
            short* Vn = Vt[cur ^ 1];
            *(s16x8*)(Kn + so0) = k0r;
            *(s16x8*)(Kn + so1) = k1r;
            *(s16x8*)(Vn + so0) = v0r;
            *(s16x8*)(Vn + so1) = v1r;
        }
        __syncthreads();
        cur ^= 1;
    }

    // epilogue: O / l -> y
#pragma unroll
    for (int mi = 0; mi < 2; ++mi)
#pragma unroll
        for (int r = 0; r < 4; ++r) {
            float inv = 1.0f / lrow[mi][r];
#pragma unroll
            for (int nd = 0; nd < 4; ++nd) {
                float v = ov[mi][nd][r] * inv;
                y[(rowbase + qrow0 + mi * 16 + hi * 4 + r) * 768 + h * 64 + nd * 16 + lo] = f2bf(v);
            }
        }
}

// ---------------- launch ----------------

extern "C" void kernel_launch(void* const* d_in, const int* in_sizes, int n_in,
                              void* d_out, int out_size, void* d_ws, size_t ws_size,
                              hipStream_t stream) {
    const float* x      = (const float*)d_in[0];
    const float* w_attn = (const float*)d_in[1];
    const float* b_attn = (const float*)d_in[2];
    const float* w_proj = (const float*)d_in[3];
    const float* b_proj = (const float*)d_in[4];

    char* ws = (char*)d_ws;
    short* x_bf = (short*)ws;                      // 16384*768*2   = 25165824  (reused as vt after gemm1)
    short* qkv  = (short*)(ws + 25165824);         // 16384*2304*2  = 75497472
    short* yb   = (short*)(ws + 100663296);        // 16384*768*2   = 25165824
    short* waT  = (short*)(ws + 125829120);        // 2304*768*2    = 3538944
    short* wpT  = (short*)(ws + 129368064);        // 768*768*2     = 1179648
    short* vt   = x_bf;                            // alias: x_bf dead after gemm1

    // x -> bf16
    convert_f32_bf16<<<dim3(12288), dim3(256), 0, stream>>>(x, x_bf, 3145728);
    // weight transposes (to [N][K] bf16)
    transpose_w<<<dim3(12, 36), dim3(256), 0, stream>>>(w_attn, waT, 768, 2304);
    transpose_w<<<dim3(12, 12), dim3(256), 0, stream>>>(w_proj, wpT, 768, 768);
    // QKV projection (+bias, q scaled by 1/8*log2e)
    gemm_bt<1><<<dim3(18, 128), dim3(256), 0, stream>>>(x_bf, waT, b_attn,
                                                        (float*)nullptr, qkv, 16384, 2304, 768);
    // V^T per head
    transpose_v<<<dim3(16, 12, 16), dim3(256), 0, stream>>>(qkv, vt);
    // causal flash attention
    flash_attn2<<<dim3(8, 12, 16), dim3(256), 0, stream>>>(qkv, vt, yb);
    // output projection -> fp32
    gemm_bt<0><<<dim3(6, 128), dim3(256), 0, stream>>>(yb, wpT, b_proj,
                                                       (float*)d_out, (short*)nullptr, 16384, 768, 768);
}

// Round 3
// 318.441 us; speedup vs baseline: 1.1546x; 1.0647x over previous
//
#include <hip/hip_runtime.h>
#include <hip/hip_bf16.h>

typedef __attribute__((ext_vector_type(4))) float f32x4;
typedef __attribute__((ext_vector_type(8))) short s16x8;
typedef __attribute__((ext_vector_type(4))) short s16x4;

#define AS1 __attribute__((address_space(1)))
#define AS3 __attribute__((address_space(3)))

__device__ __forceinline__ short f2bf(float f) {
    union { float f; unsigned u; } a; a.f = f;
    unsigned r = a.u + 0x7fff + ((a.u >> 16) & 1);
    return (short)(r >> 16);
}

__device__ __forceinline__ unsigned pk_bf16(float a, float b) {
    unsigned r;
    asm("v_cvt_pk_bf16_f32 %0, %1, %2" : "=v"(r) : "v"(a), "v"(b));
    return r;
}

// ---------------- conversion kernels ----------------

__global__ __launch_bounds__(256) void convert_f32_bf16(const float* __restrict__ in,
                                                        short* __restrict__ out, int n4) {
    int i = blockIdx.x * 256 + threadIdx.x;
    if (i < n4) {
        f32x4 v = *(const f32x4*)(in + (long)i * 4);
        s16x4 o;
        o.x = f2bf(v.x); o.y = f2bf(v.y); o.z = f2bf(v.z); o.w = f2bf(v.w);
        *(s16x4*)(out + (long)i * 4) = o;
    }
}

// src [K][N] f32 -> dst [N][K] bf16
__global__ __launch_bounds__(256) void transpose_w(const float* __restrict__ src,
                                                   short* __restrict__ dst, int K, int N) {
    __shared__ short t[64][65];
    int k0 = blockIdx.x * 64, n0 = blockIdx.y * 64;
    int tid = threadIdx.x;
    for (int i = tid; i < 64 * 64; i += 256) {
        int r = i >> 6, c = i & 63;
        t[r][c] = f2bf(src[(long)(k0 + r) * N + n0 + c]);
    }
    __syncthreads();
    for (int i = tid; i < 64 * 64; i += 256) {
        int r = i >> 6, c = i & 63;
        dst[(long)(n0 + r) * K + k0 + c] = t[c][r];
    }
}

// V part of qkv [B*T][2304] -> vt [(b*12+h)*64 + d][1024] (V^T per head)
__global__ __launch_bounds__(256) void transpose_v(const short* __restrict__ qkv,
                                                   short* __restrict__ vt) {
    __shared__ short t[64][72];
    int t0 = blockIdx.x * 64;
    int h = blockIdx.y, b = blockIdx.z;
    int tid = threadIdx.x;
#pragma unroll
    for (int i = 0; i < 2; ++i) {
        int j = tid + i * 256;
        int r = j >> 3, c = j & 7;
        s16x8 v = *(const s16x8*)(qkv + (long)(b * 1024 + t0 + r) * 2304 + 1536 + h * 64 + c * 8);
#pragma unroll
        for (int e = 0; e < 8; ++e) t[c * 8 + e][r] = v[e];
    }
    __syncthreads();
#pragma unroll
    for (int i = 0; i < 2; ++i) {
        int j = tid + i * 256;
        int r = j >> 3, c = j & 7;
        *(s16x8*)(vt + ((long)(b * 12 + h) * 64 + r) * 1024 + t0 + c * 8) = *(const s16x8*)&t[r][c * 8];
    }
}

// ---------------- GEMM: C = A @ BT^T + bias ----------------
// MODE 0: f32 out + bias.  MODE 1: bf16 out + bias, cols<768 scaled (q-scale * log2e fold)

template <int MODE>
__global__ __launch_bounds__(256) void gemm_bt(const short* __restrict__ A,
                                               const short* __restrict__ BT,
                                               const float* __restrict__ bias,
                                               float* __restrict__ outF,
                                               short* __restrict__ outH,
                                               int M, int N, int K) {
    __shared__ short lA[128 * 32];
    __shared__ short lB[128 * 32];
    int tid = threadIdx.x;
    int lane = tid & 63, w = tid >> 6;
    int wr = w >> 1, wc = w & 1;
    int lo = lane & 15, hi = lane >> 4;
    int m0 = blockIdx.y * 128, n0 = blockIdx.x * 128;

    f32x4 acc[4][4];
#pragma unroll
    for (int i = 0; i < 4; ++i)
#pragma unroll
        for (int j = 0; j < 4; ++j) acc[i][j] = (f32x4){0.f, 0.f, 0.f, 0.f};

    const short* Abase = A + (long)m0 * K;
    const short* Bbase = BT + (long)n0 * K;

    for (int k0 = 0; k0 < K; k0 += 32) {
        __syncthreads();
#pragma unroll
        for (int i = 0; i < 2; ++i) {
            int c = (w * 2 + i) * 64 + lane;
            const short* ga = Abase + (long)(c >> 2) * K + k0 + (c & 3) * 8;
            const short* gb = Bbase + (long)(c >> 2) * K + k0 + (c & 3) * 8;
            __builtin_amdgcn_global_load_lds((const AS1 void*)ga,
                                             (AS3 void*)(lA + (w * 2 + i) * 512), 16, 0, 0);
            __builtin_amdgcn_global_load_lds((const AS1 void*)gb,
                                             (AS3 void*)(lB + (w * 2 + i) * 512), 16, 0, 0);
        }
        __syncthreads();

        s16x8 a[4], b[4];
#pragma unroll
        for (int mi = 0; mi < 4; ++mi)
            a[mi] = *(const s16x8*)(lA + (wr * 64 + mi * 16 + lo) * 32 + hi * 8);
#pragma unroll
        for (int ni = 0; ni < 4; ++ni)
            b[ni] = *(const s16x8*)(lB + (wc * 64 + ni * 16 + lo) * 32 + hi * 8);
#pragma unroll
        for (int mi = 0; mi < 4; ++mi)
#pragma unroll
            for (int ni = 0; ni < 4; ++ni)
                acc[mi][ni] = __builtin_amdgcn_mfma_f32_16x16x32_bf16(a[mi], b[ni], acc[mi][ni], 0, 0, 0);
    }

#pragma unroll
    for (int mi = 0; mi < 4; ++mi)
#pragma unroll
        for (int ni = 0; ni < 4; ++ni)
#pragma unroll
            for (int r = 0; r < 4; ++r) {
                int gm = m0 + wr * 64 + mi * 16 + hi * 4 + r;
                int gn = n0 + wc * 64 + ni * 16 + lo;
                float v = acc[mi][ni][r] + bias[gn];
                if (MODE == 1) {
                    if (gn < 768) v *= 0.180336880f;  // (1/8) * log2(e)
                    outH[(long)gm * N + gn] = f2bf(v);
                } else {
                    outF[(long)gm * N + gn] = v;
                }
            }
}

// ---------------- flash attention v3: zero-LDS, swapped-operand ----------------
// qkv [B*T][2304] bf16 (q pre-scaled by 0.125*log2e). vtg = V^T per head [(b*12+h)*64+d][1024].
// y [B*T][768] bf16. 1536 blocks x 256 thr = 4 independent waves x 32 q-rows.
// Block swizzle groups all 8 qb of one (b,h) onto one XCD for L2 KV locality.

__global__ __launch_bounds__(256) void flash_attn3(const short* __restrict__ qkv,
                                                   const short* __restrict__ vtg,
                                                   short* __restrict__ y) {
    int d = blockIdx.x;
    int g = (d & 7) + 8 * (d >> 6);   // head-group 0..191, constant per XCD chunk
    int qb = (d >> 3) & 7;
    int h = g % 12, b = g / 12;
    int tid = threadIdx.x;
    int lane = tid & 63, w = tid >> 6;
    int lo = lane & 15, hi = lane >> 4;
    int hi2 = hi >> 1;
    long rowbase = (long)b * 1024;
    int qrow0 = qb * 128 + w * 32;
    const short* kbase = qkv + rowbase * 2304 + 768 + h * 64;
    const short* vbase = vtg + (long)(b * 12 + h) * 64 * 1024;

    // Q B-frags: lane holds Q[q=mi*16+lo][d=kc*32+hi*8+e]
    s16x8 bq[2][2];
#pragma unroll
    for (int mi = 0; mi < 2; ++mi)
#pragma unroll
        for (int kc = 0; kc < 2; ++kc)
            bq[mi][kc] = *(const s16x8*)(qkv + (rowbase + qrow0 + mi * 16 + lo) * 2304 +
                                         h * 64 + kc * 32 + hi * 8);

    f32x4 ov[2][4];   // O^T: d = nd*16+hi*4+r, q = mi*16+lo
    float mrun[2], lrun[2];
#pragma unroll
    for (int mi = 0; mi < 2; ++mi) {
        mrun[mi] = -3.0e38f; lrun[mi] = 0.f;
#pragma unroll
        for (int nd = 0; nd < 4; ++nd) ov[mi][nd] = (f32x4){0.f, 0.f, 0.f, 0.f};
    }

    int sA = ((hi & 1) * 2) * 16 + lo;  // shfl src for frag words j=0,1
    int sB = sA + 16;                   // j=2,3

    int kvEnd = qrow0 + 32;
    for (int kv0 = 0; kv0 < kvEnd; kv0 += 64) {
        // ---- S^T = K Q^T : lane holds S[kv=n*16+hi*4+r][q=mi*16+lo]
        f32x4 s[2][4];
#pragma unroll
        for (int n = 0; n < 4; ++n) {
            const short* kr = kbase + (long)(kv0 + n * 16 + lo) * 2304;
            s16x8 kf0 = *(const s16x8*)(kr + hi * 8);
            s16x8 kf1 = *(const s16x8*)(kr + 32 + hi * 8);
#pragma unroll
            for (int mi = 0; mi < 2; ++mi) {
                f32x4 t = (f32x4){0.f, 0.f, 0.f, 0.f};
                t = __builtin_amdgcn_mfma_f32_16x16x32_bf16(kf0, bq[mi][0], t, 0, 0, 0);
                t = __builtin_amdgcn_mfma_f32_16x16x32_bf16(kf1, bq[mi][1], t, 0, 0, 0);
                s[mi][n] = t;
            }
        }

        // ---- softmax (in-register, per-lane q=lo) + P -> B-frags
        s16x8 ap[2][2];
#pragma unroll
        for (int mi = 0; mi < 2; ++mi) {
            int qglob = qrow0 + mi * 16 + lo;
            if (kv0 + 63 > qrow0 + mi * 16) {
#pragma unroll
                for (int n = 0; n < 4; ++n)
#pragma unroll
                    for (int r = 0; r < 4; ++r)
                        if (kv0 + n * 16 + hi * 4 + r > qglob) s[mi][n][r] = -3.0e38f;
            }
            float mx = s[mi][0][0];
#pragma unroll
            for (int n = 0; n < 4; ++n)
#pragma unroll
                for (int r = 0; r < 4; ++r) mx = fmaxf(mx, s[mi][n][r]);
            mx = fmaxf(mx, __shfl_xor(mx, 16));
            mx = fmaxf(mx, __shfl_xor(mx, 32));
            float mn = fmaxf(mrun[mi], mx);
            float alpha = exp2f(mrun[mi] - mn);
            mrun[mi] = mn;
            float rs = 0.f;
#pragma unroll
            for (int n = 0; n < 4; ++n)
#pragma unroll
                for (int r = 0; r < 4; ++r) {
                    float p = exp2f(s[mi][n][r] - mn);
                    s[mi][n][r] = p;
                    rs += p;
                }
            rs += __shfl_xor(rs, 16);
            rs += __shfl_xor(rs, 32);
            lrun[mi] = lrun[mi] * alpha + rs;
#pragma unroll
            for (int nd = 0; nd < 4; ++nd)
#pragma unroll
                for (int r = 0; r < 4; ++r) ov[mi][nd][r] *= alpha;

            // pack P rows to bf16 pairs: W[n][w] covers kv = n*16+hi*4 + {2w, 2w+1}
            unsigned W[4][2];
#pragma unroll
            for (int n = 0; n < 4; ++n) {
                W[n][0] = pk_bf16(s[mi][n][0], s[mi][n][1]);
                W[n][1] = pk_bf16(s[mi][n][2], s[mi][n][3]);
            }
            // exchange: frag word j = W[kc*2+(hi>>1)][j&1] from lane ((hi&1)*2+(j>>1))*16+lo
#pragma unroll
            for (int kc = 0; kc < 2; ++kc) {
                unsigned a0 = __shfl(W[kc * 2][0], sA), b0 = __shfl(W[kc * 2 + 1][0], sA);
                unsigned a1 = __shfl(W[kc * 2][1], sA), b1 = __shfl(W[kc * 2 + 1][1], sA);
                unsigned a2 = __shfl(W[kc * 2][0], sB), b2 = __shfl(W[kc * 2 + 1][0], sB);
                unsigned a3 = __shfl(W[kc * 2][1], sB), b3 = __shfl(W[kc * 2 + 1][1], sB);
                unsigned q0 = hi2 ? b0 : a0;
                unsigned q1 = hi2 ? b1 : a1;
                unsigned q2 = hi2 ? b2 : a2;
                unsigned q3 = hi2 ? b3 : a3;
                union { unsigned u[4]; s16x8 v; } cv;
                cv.u[0] = q0; cv.u[1] = q1; cv.u[2] = q2; cv.u[3] = q3;
                ap[mi][kc] = cv.v;
            }
        }

        // ---- O^T += V^T P^T : A = V^T-frag, B = P-frag
#pragma unroll
        for (int nd = 0; nd < 4; ++nd) {
            const short* vr = vbase + (long)(nd * 16 + lo) * 1024 + kv0;
            s16x8 av0 = *(const s16x8*)(vr + hi * 8);
            s16x8 av1 = *(const s16x8*)(vr + 32 + hi * 8);
#pragma unroll
            for (int mi = 0; mi < 2; ++mi) {
                ov[mi][nd] = __builtin_amdgcn_mfma_f32_16x16x32_bf16(av0, ap[mi][0], ov[mi][nd], 0, 0, 0);
                ov[mi][nd] = __builtin_amdgcn_mfma_f32_16x16x32_bf16(av1, ap[mi][1], ov[mi][nd], 0, 0, 0);
            }
        }
    }

    // ---- epilogue: y[q][h*64+d] = O^T[d][q] / l[q]  (u32-packed along d)
#pragma unroll
    for (int mi = 0; mi < 2; ++mi) {
        float inv = 1.0f / lrun[mi];
        long row = (rowbase + qrow0 + mi * 16 + lo) * 768 + h * 64;
#pragma unroll
        for (int nd = 0; nd < 4; ++nd)
#pragma unroll
            for (int j2 = 0; j2 < 2; ++j2) {
                unsigned pv = pk_bf16(ov[mi][nd][2 * j2] * inv, ov[mi][nd][2 * j2 + 1] * inv);
                *(unsigned*)(y + row + nd * 16 + hi * 4 + 2 * j2) = pv;
            }
    }
}

// ---------------- launch ----------------

extern "C" void kernel_launch(void* const* d_in, const int* in_sizes, int n_in,
                              void* d_out, int out_size, void* d_ws, size_t ws_size,
                              hipStream_t stream) {
    const float* x      = (const float*)d_in[0];
    const float* w_attn = (const float*)d_in[1];
    const float* b_attn = (const float*)d_in[2];
    const float* w_proj = (const float*)d_in[3];
    const float* b_proj = (const float*)d_in[4];

    char* ws = (char*)d_ws;
    short* x_bf = (short*)ws;                      // 16384*768*2   = 25165824  (reused as vt after gemm1)
    short* qkv  = (short*)(ws + 25165824);         // 16384*2304*2  = 75497472
    short* yb   = (short*)(ws + 100663296);        // 16384*768*2   = 25165824
    short* waT  = (short*)(ws + 125829120);        // 2304*768*2    = 3538944
    short* wpT  = (short*)(ws + 129368064);        // 768*768*2     = 1179648
    short* vt   = x_bf;                            // alias: x_bf dead after gemm1

    // x -> bf16
    convert_f32_bf16<<<dim3(12288), dim3(256), 0, stream>>>(x, x_bf, 3145728);
    // weight transposes (to [N][K] bf16)
    transpose_w<<<dim3(12, 36), dim3(256), 0, stream>>>(w_attn, waT, 768, 2304);
    transpose_w<<<dim3(12, 12), dim3(256), 0, stream>>>(w_proj, wpT, 768, 768);
    // QKV projection (+bias, q scaled by 1/8*log2e)
    gemm_bt<1><<<dim3(18, 128), dim3(256), 0, stream>>>(x_bf, waT, b_attn,
                                                        (float*)nullptr, qkv, 16384, 2304, 768);
    // V^T per head
    transpose_v<<<dim3(16, 12, 16), dim3(256), 0, stream>>>(qkv, vt);
    // causal flash attention (zero-LDS)
    flash_attn3<<<dim3(1536), dim3(256), 0, stream>>>(qkv, vt, yb);
    // output projection -> fp32
    gemm_bt<0><<<dim3(6, 128), dim3(256), 0, stream>>>(yb, wpT, b_proj,
                                                       (float*)d_out, (short*)nullptr, 16384, 768, 768);
}